// Round 9
// baseline (203.670 us; speedup 1.0000x reference)
//
#include <hip/hip_runtime.h>
#include <hip/hip_bf16.h>

// Problem: B=4, S=2048, D=1024, H=16, hd=64. MHA w/ RoPE, causal, out f32.
// Round 8: attn — drop V LDS staging (V^T fragments loaded direct from global,
// issued right after QK^T; L2-resident, consumed after softmax). LDS 48->32KB
// => 4 blocks/CU. K staging + P LDS unchanged (isolation).

typedef __bf16 bf16x8 __attribute__((ext_vector_type(8)));
typedef float f32x4 __attribute__((ext_vector_type(4)));
typedef unsigned short u16x8 __attribute__((ext_vector_type(8)));

#define DEV static __device__ __forceinline__

DEV unsigned short f2bf(float f) {
  unsigned int u = __builtin_bit_cast(unsigned int, f);
  u += 0x7FFFu + ((u >> 16) & 1u);   // round-to-nearest-even
  return (unsigned short)(u >> 16);
}
DEV float bf2f(unsigned short h) {
  unsigned int u = ((unsigned int)h) << 16;
  return __builtin_bit_cast(float, u);
}
DEV bf16x8 ld_bf8(const unsigned short* p) {
  union { u16x8 u; bf16x8 b; } c;
  c.u = *reinterpret_cast<const u16x8*>(p);
  return c.b;
}
// packed RNE f32x2 -> bf16x2 via HW cvt (lo=a, hi=b)
DEV unsigned int pk2(float a, float b) {
  unsigned int r;
  asm("v_cvt_pk_bf16_f32 %0, %1, %2" : "=v"(r) : "v"(a), "v"(b));
  return r;
}

// global -> LDS direct (16B/lane). dst must be wave-uniform; lane writes dst + lane*16.
DEV void gload_lds16(const unsigned short* src, unsigned short* dst) {
  __builtin_amdgcn_global_load_lds(
      (const __attribute__((address_space(1))) void*)src,
      (__attribute__((address_space(3))) void*)dst, 16, 0, 0);
}

// Stage a 128x64 bf16 tile (row stride ldg elems) into linear LDS [128][64],
// global SOURCE pre-swizzled: LDS[row][c16] = G[row][c16^(row&7)] (rule #21).
DEV void stage_tile(const unsigned short* g, int ldg, unsigned short* lds,
                    int wave, int lane) {
  int rl = lane >> 3;      // row within 8-row issue group
  int c16 = lane & 7;      // 16B chunk in row
#pragma unroll
  for (int i = 0; i < 4; ++i) {
    int row = i * 32 + wave * 8 + rl;
    int sc16 = c16 ^ (row & 7);
    const unsigned short* src = g + (size_t)row * ldg + sc16 * 8;
    unsigned short* dst = lds + (i * 32 + wave * 8) * 64;   // wave-uniform
    gload_lds16(src, dst);
  }
}

// Read one MFMA A/B fragment (8 bf16 along K) from the swizzled tile.
DEV bf16x8 lds_frag(const unsigned short* lds, int row, int c16) {
  return ld_bf8(lds + row * 64 + ((c16 ^ (row & 7)) << 3));
}

// ---------------- f32 -> bf16 convert (vectorized) ----------------
__global__ void k_f32_to_bf16(const float* __restrict__ in,
                              unsigned short* __restrict__ out, int n4) {
  int i = blockIdx.x * blockDim.x + threadIdx.x;
  if (i < n4) {
    float4 v = reinterpret_cast<const float4*>(in)[i];
    uint2 o;
    o.x = pk2(v.x, v.y);
    o.y = pk2(v.z, v.w);
    reinterpret_cast<uint2*>(out)[i] = o;
  }
}

// ---------------- RoPE cos/sin table (double precision, tiny) ----------------
__global__ void k_rope_table(const int* __restrict__ pos, float* __restrict__ tab) {
  int idx = blockIdx.x * blockDim.x + threadIdx.x; // S*32
  if (idx >= 2048 * 32) return;
  int s = idx >> 5, i = idx & 31;
  double inv = pow(10000.0, -(double)(2 * i) / 64.0);
  double ang = (double)pos[s] * inv;
  tab[idx * 2]     = (float)cos(ang);
  tab[idx * 2 + 1] = (float)sin(ang);
}

// ---------------- QKV GEMM: xb[8192x1024] @ Wcat[3072x1024]^T ----------------
// 128x128 block, 4 waves (2x2), 64x64/wave, LDS-staged, BK=64.
// Epilogue: Q,K -> RoPE applied + head-split [BH][S][64]; V -> [BH][64][S] (^T).
__global__ __launch_bounds__(256) void k_gemm_qkv(
    const unsigned short* __restrict__ A, const unsigned short* __restrict__ W,
    unsigned short* __restrict__ Qh, unsigned short* __restrict__ Kh,
    unsigned short* __restrict__ Vt, const float* __restrict__ tab) {
  const int Kd = 1024, S = 2048;
  __shared__ __align__(16) unsigned short As[128 * 64];
  __shared__ __align__(16) unsigned short Bs[128 * 64];
  int m0 = blockIdx.x * 128, n0 = blockIdx.y * 128;
  int wave = threadIdx.x >> 6, lane = threadIdx.x & 63;
  int wm = wave >> 1, wn = wave & 1;
  int lr = lane & 15, lk = lane >> 4;
  const unsigned short* Ag = A + (size_t)m0 * Kd;
  const unsigned short* Wg = W + (size_t)n0 * Kd;
  f32x4 acc[4][4] = {};
  for (int k0 = 0; k0 < Kd; k0 += 64) {
    stage_tile(Ag + k0, Kd, As, wave, lane);
    stage_tile(Wg + k0, Kd, Bs, wave, lane);
    __syncthreads();
#pragma unroll
    for (int ks = 0; ks < 2; ++ks) {
      bf16x8 a[4], b[4];
#pragma unroll
      for (int fm = 0; fm < 4; ++fm) a[fm] = lds_frag(As, wm * 64 + fm * 16 + lr, ks * 4 + lk);
#pragma unroll
      for (int fn = 0; fn < 4; ++fn) b[fn] = lds_frag(Bs, wn * 64 + fn * 16 + lr, ks * 4 + lk);
#pragma unroll
      for (int fm = 0; fm < 4; ++fm)
#pragma unroll
        for (int fn = 0; fn < 4; ++fn)
          acc[fm][fn] = __builtin_amdgcn_mfma_f32_16x16x32_bf16(a[fm], b[fn], acc[fm][fn], 0, 0, 0);
    }
    __syncthreads();
  }
  int t = n0 >> 10;   // uniform per block (128 | 1024)
  if (t == 2) {
    // V: store transposed -> Vt[bh][d][s]
#pragma unroll
    for (int fm = 0; fm < 4; ++fm) {
      int row = m0 + wm * 64 + fm * 16 + lk * 4;
      int bb = row >> 11, s0 = row & 2047;
#pragma unroll
      for (int fn = 0; fn < 4; ++fn) {
        int col = n0 + wn * 64 + fn * 16 + lr;
        int h = (col >> 6) & 15, d = col & 63;
        uint2 w;
        w.x = pk2(acc[fm][fn][0], acc[fm][fn][1]);
        w.y = pk2(acc[fm][fn][2], acc[fm][fn][3]);
        *reinterpret_cast<uint2*>(Vt + (((size_t)(bb * 16 + h) * 64) + d) * S + s0) = w;
      }
    }
  } else {
    // Q/K: apply RoPE on f32 accumulators (pairs = adjacent lanes), then store.
    unsigned short* dst0 = (t == 0) ? Qh : Kh;
#pragma unroll
    for (int fm = 0; fm < 4; ++fm) {
      int row = m0 + wm * 64 + fm * 16 + lk * 4;
#pragma unroll
      for (int fn = 0; fn < 4; ++fn) {
        int col = n0 + wn * 64 + fn * 16 + lr;
        int h = (col >> 6) & 15, d = col & 63;
        int ri = d >> 1;
        bool odd = d & 1;
#pragma unroll
        for (int r = 0; r < 4; ++r) {
          int rr = row + r;
          int bb = rr >> 11, s = rr & 2047;
          float2 cs = reinterpret_cast<const float2*>(tab)[s * 32 + ri];
          float v = acc[fm][fn][r];
          float other = __shfl_xor(v, 1);
          float res = odd ? (other * cs.y + v * cs.x)     // x1*sin + x2*cos
                          : (v * cs.x - other * cs.y);    // x1*cos - x2*sin
          dst0[(((size_t)(bb * 16 + h) * S) + s) * 64 + d] = f2bf(res);
        }
      }
    }
  }
}

// ---------------- Flash attention (swapped-QK^T, transposed-O) ----------------
// grid (BH=64, 16), 4 waves/block, each wave owns 32 q-rows. K tiles staged in
// LDS (double-buffered, global_load_lds). V^T fragments loaded DIRECT from
// global (L2-resident), issued right after QK^T, consumed after softmax.
__global__ __launch_bounds__(256) void k_attn(
    const unsigned short* __restrict__ Qh, const unsigned short* __restrict__ Kh,
    const unsigned short* __restrict__ Vt, unsigned short* __restrict__ Obuf) {
  const int S = 2048;
  const float KF = 0.18033688f;          // 0.125 * log2(e)
  const float RAW_THR = 44.3614f;        // 8 log2-units in raw-score domain
  int bh = blockIdx.x;
  int b = bh >> 4, h = bh & 15;
  int wave = threadIdx.x >> 6, lane = threadIdx.x & 63;
  int lr = lane & 15, lk = lane >> 4;
  int qt = (int)gridDim.y - 1 - (int)blockIdx.y;   // heavy tiles dispatch first
  int q0 = qt * 128 + wave * 32;
  const unsigned short* Qp = Qh + (size_t)bh * S * 64;
  const unsigned short* Kp = Kh + (size_t)bh * S * 64;
  const unsigned short* Vp = Vt + (size_t)bh * 64 * S;

  __shared__ __align__(16) unsigned short Ks[2][64 * 64];   // 16 KB
  __shared__ __align__(16) unsigned short P_all[4][32][64]; // 16 KB
  char* pw = (char*)&P_all[wave][0][0];

  // stage K rows kv0..kv0+63 into buf
  auto STAGE = [&](int buf, int kv0) {
    int rl = lane >> 3, c16 = lane & 7;
#pragma unroll
    for (int i = 0; i < 2; ++i) {
      int row = wave * 16 + i * 8 + rl;
      int sc = (c16 ^ (row & 7)) << 3;
      gload_lds16(Kp + (size_t)(kv0 + row) * 64 + sc, &Ks[buf][(wave * 16 + i * 8) * 64]);
    }
  };

  bf16x8 qb[2][2];
#pragma unroll
  for (int mi = 0; mi < 2; ++mi)
#pragma unroll
    for (int ks = 0; ks < 2; ++ks)
      qb[mi][ks] = ld_bf8(Qp + (size_t)(q0 + mi * 16 + lr) * 64 + ks * 32 + lk * 8);

  f32x4 acc_o[4][2] = {};                 // O^T: [nf=d-blk][mi]: row=d, col=q
  float m_run[2] = {-1e30f, -1e30f}, l_run[2] = {0.f, 0.f};
  int my_nt = (q0 + 31) / 64 + 1;
  int NT = 2 * qt + 2;                    // max ntiles over the 4 waves

  STAGE(0, 0);
  __syncthreads();                        // drains vmcnt -> buf0 ready

  for (int t = 0; t < NT; ++t) {
    int cur = t & 1;
    if (t + 1 < NT) STAGE(cur ^ 1, (t + 1) * 64);   // async prefetch next K tile
    if (t < my_nt) {
      int kv0 = t * 64;
      // K fragments from LDS (A operand of S^T = K·Q^T)
      bf16x8 ka[4][2];
#pragma unroll
      for (int ni = 0; ni < 4; ++ni)
#pragma unroll
        for (int ks = 0; ks < 2; ++ks)
          ka[ni][ks] = lds_frag(&Ks[cur][0], ni * 16 + lr, ks * 4 + lk);
      f32x4 st[4][2] = {};
      __builtin_amdgcn_s_setprio(1);
#pragma unroll
      for (int ni = 0; ni < 4; ++ni)
#pragma unroll
        for (int mi = 0; mi < 2; ++mi) {
          st[ni][mi] = __builtin_amdgcn_mfma_f32_16x16x32_bf16(ka[ni][0], qb[mi][0], st[ni][mi], 0, 0, 0);
          st[ni][mi] = __builtin_amdgcn_mfma_f32_16x16x32_bf16(ka[ni][1], qb[mi][1], st[ni][mi], 0, 0, 0);
        }
      __builtin_amdgcn_s_setprio(0);
      // V fragments DIRECT from global (A operand of O^T = V^T·P^T) —
      // issued here, ~full softmax of slack before first use in PV.
      bf16x8 va[4][2];
#pragma unroll
      for (int nf = 0; nf < 4; ++nf)
#pragma unroll
        for (int ks = 0; ks < 2; ++ks)
          va[nf][ks] = ld_bf8(Vp + (size_t)(nf * 16 + lr) * S + kv0 + ks * 32 + lk * 8);

      if (kv0 + 63 > q0) {   // causal mask (wave-uniform branch)
#pragma unroll
        for (int mi = 0; mi < 2; ++mi) {
          int row = q0 + mi * 16 + lr;
#pragma unroll
          for (int ni = 0; ni < 4; ++ni)
#pragma unroll
            for (int r = 0; r < 4; ++r)
              if (kv0 + ni * 16 + lk * 4 + r > row) st[ni][mi][r] = -3e38f;
        }
      }
      // per-lane row max (in-lane tree + 2 shfl)
      float mx[2];
#pragma unroll
      for (int mi = 0; mi < 2; ++mi) {
        float a0 = fmaxf(fmaxf(st[0][mi][0], st[0][mi][1]), fmaxf(st[0][mi][2], st[0][mi][3]));
        float a1 = fmaxf(fmaxf(st[1][mi][0], st[1][mi][1]), fmaxf(st[1][mi][2], st[1][mi][3]));
        float a2 = fmaxf(fmaxf(st[2][mi][0], st[2][mi][1]), fmaxf(st[2][mi][2], st[2][mi][3]));
        float a3 = fmaxf(fmaxf(st[3][mi][0], st[3][mi][1]), fmaxf(st[3][mi][2], st[3][mi][3]));
        float m = fmaxf(fmaxf(a0, a1), fmaxf(a2, a3));
        m = fmaxf(m, __shfl_xor(m, 16));
        m = fmaxf(m, __shfl_xor(m, 32));
        mx[mi] = m;
      }
      // defer-max (T13): rescale only if some row's max grew past threshold
      bool small = (mx[0] <= m_run[0] + RAW_THR) && (mx[1] <= m_run[1] + RAW_THR);
      if (!__all(small)) {
#pragma unroll
        for (int mi = 0; mi < 2; ++mi) {
          float m_new = fmaxf(m_run[mi], mx[mi]);
          float scale = __builtin_amdgcn_exp2f((m_run[mi] - m_new) * KF);
          l_run[mi] *= scale;
          m_run[mi] = m_new;
#pragma unroll
          for (int nf = 0; nf < 4; ++nf)
#pragma unroll
            for (int r = 0; r < 4; ++r) acc_o[nf][mi][r] *= scale;
        }
      }
      // P = exp2(st*KF - m*KF), HW-packed bf16, swizzled 8B LDS writes
#pragma unroll
      for (int mi = 0; mi < 2; ++mi) {
        float negh = -m_run[mi] * KF;
        int prow = mi * 16 + lr;
        char* rowp = pw + prow * 128;
        int swz = (lr & 7) << 4;
        float rs = 0.f;
#pragma unroll
        for (int ni = 0; ni < 4; ++ni) {
          float p0 = __builtin_amdgcn_exp2f(fmaf(st[ni][mi][0], KF, negh));
          float p1 = __builtin_amdgcn_exp2f(fmaf(st[ni][mi][1], KF, negh));
          float p2 = __builtin_amdgcn_exp2f(fmaf(st[ni][mi][2], KF, negh));
          float p3 = __builtin_amdgcn_exp2f(fmaf(st[ni][mi][3], KF, negh));
          rs += (p0 + p1) + (p2 + p3);
          uint2 w; w.x = pk2(p0, p1); w.y = pk2(p2, p3);
          *reinterpret_cast<uint2*>(rowp + ((ni * 32 + lk * 8) ^ swz)) = w;
        }
        rs += __shfl_xor(rs, 16);
        rs += __shfl_xor(rs, 32);
        l_run[mi] += rs;
      }
      // PV: O^T += V^T · P^T  (P as B operand from swizzled LDS)
      bf16x8 pb[2][2];
#pragma unroll
      for (int mi = 0; mi < 2; ++mi) {
        int prow = mi * 16 + lr;
        int swz = (lr & 7) << 4;
#pragma unroll
        for (int ks = 0; ks < 2; ++ks)
          pb[mi][ks] = ld_bf8((const unsigned short*)(pw + prow * 128 + ((ks * 64 + lk * 16) ^ swz)));
      }
      __builtin_amdgcn_s_setprio(1);
#pragma unroll
      for (int nf = 0; nf < 4; ++nf)
#pragma unroll
        for (int mi = 0; mi < 2; ++mi) {
          acc_o[nf][mi] = __builtin_amdgcn_mfma_f32_16x16x32_bf16(va[nf][0], pb[mi][0], acc_o[nf][mi], 0, 0, 0);
          acc_o[nf][mi] = __builtin_amdgcn_mfma_f32_16x16x32_bf16(va[nf][1], pb[mi][1], acc_o[nf][mi], 0, 0, 0);
        }
      __builtin_amdgcn_s_setprio(0);
    }
    __syncthreads();   // drains vmcnt (stage done) + orders LDS reuse
  }

  // epilogue: O[q][d] = O^T[d][q] / l ; packed 8B stores
#pragma unroll
  for (int mi = 0; mi < 2; ++mi) {
    float inv_l = 1.f / l_run[mi];
    int q = q0 + mi * 16 + lr;
    size_t base = ((size_t)b * S + q) * 1024 + h * 64;
#pragma unroll
    for (int nf = 0; nf < 4; ++nf) {
      uint2 w;
      w.x = pk2(acc_o[nf][mi][0] * inv_l, acc_o[nf][mi][1] * inv_l);
      w.y = pk2(acc_o[nf][mi][2] * inv_l, acc_o[nf][mi][3] * inv_l);
      *reinterpret_cast<uint2*>(Obuf + base + nf * 16 + lk * 4) = w;
    }
  }
}

// ---------------- Output GEMM: Obuf[8192x1024] @ Wo[1024x1024]^T -> f32 ----------------
__global__ __launch_bounds__(256) void k_gemm_out(
    const unsigned short* __restrict__ A, const unsigned short* __restrict__ W,
    float* __restrict__ C) {
  const int Kd = 1024;
  __shared__ __align__(16) unsigned short As[128 * 64];
  __shared__ __align__(16) unsigned short Bs[128 * 64];
  int m0 = blockIdx.x * 128, n0 = blockIdx.y * 128;
  int wave = threadIdx.x >> 6, lane = threadIdx.x & 63;
  int wm = wave >> 1, wn = wave & 1;
  int lr = lane & 15, lk = lane >> 4;
  const unsigned short* Ag = A + (size_t)m0 * Kd;
  const unsigned short* Wg = W + (size_t)n0 * Kd;
  f32x4 acc[4][4] = {};
  for (int k0 = 0; k0 < Kd; k0 += 64) {
    stage_tile(Ag + k0, Kd, As, wave, lane);
    stage_tile(Wg + k0, Kd, Bs, wave, lane);
    __syncthreads();
#pragma unroll
    for (int ks = 0; ks < 2; ++ks) {
      bf16x8 a[4], b[4];
#pragma unroll
      for (int fm = 0; fm < 4; ++fm) a[fm] = lds_frag(As, wm * 64 + fm * 16 + lr, ks * 4 + lk);
#pragma unroll
      for (int fn = 0; fn < 4; ++fn) b[fn] = lds_frag(Bs, wn * 64 + fn * 16 + lr, ks * 4 + lk);
#pragma unroll
      for (int fm = 0; fm < 4; ++fm)
#pragma unroll
        for (int fn = 0; fn < 4; ++fn)
          acc[fm][fn] = __builtin_amdgcn_mfma_f32_16x16x32_bf16(a[fm], b[fn], acc[fm][fn], 0, 0, 0);
    }
    __syncthreads();
  }
#pragma unroll
  for (int fm = 0; fm < 4; ++fm)
#pragma unroll
    for (int fn = 0; fn < 4; ++fn)
#pragma unroll
      for (int r = 0; r < 4; ++r)
        C[(size_t)(m0 + wm * 64 + fm * 16 + lk * 4 + r) * 1024 + n0 + wn * 64 + fn * 16 + lr] =
            acc[fm][fn][r];
}

extern "C" void kernel_launch(void* const* d_in, const int* in_sizes, int n_in,
                              void* d_out, int out_size, void* d_ws, size_t ws_size,
                              hipStream_t stream) {
  const float* x  = (const float*)d_in[0];
  const float* Wq = (const float*)d_in[1];
  const float* Wk = (const float*)d_in[2];
  const float* Wv = (const float*)d_in[3];
  const float* Wo = (const float*)d_in[4];
  const int* pos  = (const int*)d_in[5];
  float* out = (float*)d_out;
  char* ws = (char*)d_ws;

  // Workspace layout (bytes):
  unsigned short* xb  = (unsigned short*)(ws);              // 16 MB  x bf16 [8192][1024]
  unsigned short* Wb  = (unsigned short*)(ws + 16777216);   // 6 MB   Wq|Wk|Wv bf16 [3072][1024]
  unsigned short* Wob = (unsigned short*)(ws + 23068672);   // 2 MB   Wo bf16
  unsigned short* Qh  = (unsigned short*)(ws + 25165824);   // 16 MB  [B][H][S][64]
  unsigned short* Kh  = (unsigned short*)(ws + 41943040);   // 16 MB
  unsigned short* Ob  = (unsigned short*)(ws + 58720256);   // 16 MB  attn out bf16
  unsigned short* Vt  = (unsigned short*)(ws + 75497472);   // 16 MB  [B][H][64][S]
  float* tab          = (float*)(ws + 92274688);            // 512 KB cos/sin
  (void)in_sizes; (void)n_in; (void)out_size; (void)ws_size;

  k_f32_to_bf16<<<8192, 256, 0, stream>>>(x, xb, 2097152);
  k_f32_to_bf16<<<1024, 256, 0, stream>>>(Wq, Wb, 262144);
  k_f32_to_bf16<<<1024, 256, 0, stream>>>(Wk, Wb + 1048576, 262144);
  k_f32_to_bf16<<<1024, 256, 0, stream>>>(Wv, Wb + 2097152, 262144);
  k_f32_to_bf16<<<1024, 256, 0, stream>>>(Wo, Wob, 262144);
  k_rope_table<<<256, 256, 0, stream>>>(pos, tab);

  dim3 g1(64, 24);
  k_gemm_qkv<<<g1, 256, 0, stream>>>(xb, Wb, Qh, Kh, Vt, tab);
  dim3 ga(64, 16);
  k_attn<<<ga, 256, 0, stream>>>(Qh, Kh, Vt, Ob);
  dim3 g2(64, 8);
  k_gemm_out<<<g2, 256, 0, stream>>>(Ob, Wob, out);
}

// Round 10
// 189.044 us; speedup vs baseline: 1.0774x; 1.0774x over previous
//
#include <hip/hip_runtime.h>
#include <hip/hip_bf16.h>

// Problem: B=4, S=2048, D=1024, H=16, hd=64. MHA w/ RoPE, causal, out f32.
// Round 9: revert attn to R7 (V staged in LDS — R8's direct-V regressed);
// merge the 4 weight f32->bf16 converts into one launch.

typedef __bf16 bf16x8 __attribute__((ext_vector_type(8)));
typedef float f32x4 __attribute__((ext_vector_type(4)));
typedef unsigned short u16x8 __attribute__((ext_vector_type(8)));

#define DEV static __device__ __forceinline__

DEV unsigned short f2bf(float f) {
  unsigned int u = __builtin_bit_cast(unsigned int, f);
  u += 0x7FFFu + ((u >> 16) & 1u);   // round-to-nearest-even
  return (unsigned short)(u >> 16);
}
DEV float bf2f(unsigned short h) {
  unsigned int u = ((unsigned int)h) << 16;
  return __builtin_bit_cast(float, u);
}
DEV bf16x8 ld_bf8(const unsigned short* p) {
  union { u16x8 u; bf16x8 b; } c;
  c.u = *reinterpret_cast<const u16x8*>(p);
  return c.b;
}
// packed RNE f32x2 -> bf16x2 via HW cvt (lo=a, hi=b)
DEV unsigned int pk2(float a, float b) {
  unsigned int r;
  asm("v_cvt_pk_bf16_f32 %0, %1, %2" : "=v"(r) : "v"(a), "v"(b));
  return r;
}

// global -> LDS direct (16B/lane). dst must be wave-uniform; lane writes dst + lane*16.
DEV void gload_lds16(const unsigned short* src, unsigned short* dst) {
  __builtin_amdgcn_global_load_lds(
      (const __attribute__((address_space(1))) void*)src,
      (__attribute__((address_space(3))) void*)dst, 16, 0, 0);
}

// Stage a 128x64 bf16 tile (row stride ldg elems) into linear LDS [128][64],
// global SOURCE pre-swizzled: LDS[row][c16] = G[row][c16^(row&7)] (rule #21).
DEV void stage_tile(const unsigned short* g, int ldg, unsigned short* lds,
                    int wave, int lane) {
  int rl = lane >> 3;      // row within 8-row issue group
  int c16 = lane & 7;      // 16B chunk in row
#pragma unroll
  for (int i = 0; i < 4; ++i) {
    int row = i * 32 + wave * 8 + rl;
    int sc16 = c16 ^ (row & 7);
    const unsigned short* src = g + (size_t)row * ldg + sc16 * 8;
    unsigned short* dst = lds + (i * 32 + wave * 8) * 64;   // wave-uniform
    gload_lds16(src, dst);
  }
}

// Read one MFMA A/B fragment (8 bf16 along K) from the swizzled tile.
DEV bf16x8 lds_frag(const unsigned short* lds, int row, int c16) {
  return ld_bf8(lds + row * 64 + ((c16 ^ (row & 7)) << 3));
}

// ---------------- f32 -> bf16 convert (vectorized) ----------------
__global__ void k_f32_to_bf16(const float* __restrict__ in,
                              unsigned short* __restrict__ out, int n4) {
  int i = blockIdx.x * blockDim.x + threadIdx.x;
  if (i < n4) {
    float4 v = reinterpret_cast<const float4*>(in)[i];
    uint2 o;
    o.x = pk2(v.x, v.y);
    o.y = pk2(v.z, v.w);
    reinterpret_cast<uint2*>(out)[i] = o;
  }
}

// ---------------- all 4 weight converts in one launch ----------------
__global__ void k_conv_w(const float* __restrict__ Wq, const float* __restrict__ Wk,
                         const float* __restrict__ Wv, const float* __restrict__ Wo,
                         unsigned short* __restrict__ Wb, unsigned short* __restrict__ Wob) {
  int i = blockIdx.x * blockDim.x + threadIdx.x;   // 4 x 262144 f32x4 elements
  int which = i >> 18, j = i & 262143;
  const float* src = (which == 0) ? Wq : (which == 1) ? Wk : (which == 2) ? Wv : Wo;
  unsigned short* dst = (which == 3) ? Wob : Wb + (size_t)which * 1048576;
  float4 v = reinterpret_cast<const float4*>(src)[j];
  uint2 o;
  o.x = pk2(v.x, v.y);
  o.y = pk2(v.z, v.w);
  reinterpret_cast<uint2*>(dst)[j] = o;
}

// ---------------- RoPE cos/sin table (double precision, tiny) ----------------
__global__ void k_rope_table(const int* __restrict__ pos, float* __restrict__ tab) {
  int idx = blockIdx.x * blockDim.x + threadIdx.x; // S*32
  if (idx >= 2048 * 32) return;
  int s = idx >> 5, i = idx & 31;
  double inv = pow(10000.0, -(double)(2 * i) / 64.0);
  double ang = (double)pos[s] * inv;
  tab[idx * 2]     = (float)cos(ang);
  tab[idx * 2 + 1] = (float)sin(ang);
}

// ---------------- QKV GEMM: xb[8192x1024] @ Wcat[3072x1024]^T ----------------
// 128x128 block, 4 waves (2x2), 64x64/wave, LDS-staged, BK=64.
// Epilogue: Q,K -> RoPE applied + head-split [BH][S][64]; V -> [BH][64][S] (^T).
__global__ __launch_bounds__(256) void k_gemm_qkv(
    const unsigned short* __restrict__ A, const unsigned short* __restrict__ W,
    unsigned short* __restrict__ Qh, unsigned short* __restrict__ Kh,
    unsigned short* __restrict__ Vt, const float* __restrict__ tab) {
  const int Kd = 1024, S = 2048;
  __shared__ __align__(16) unsigned short As[128 * 64];
  __shared__ __align__(16) unsigned short Bs[128 * 64];
  int m0 = blockIdx.x * 128, n0 = blockIdx.y * 128;
  int wave = threadIdx.x >> 6, lane = threadIdx.x & 63;
  int wm = wave >> 1, wn = wave & 1;
  int lr = lane & 15, lk = lane >> 4;
  const unsigned short* Ag = A + (size_t)m0 * Kd;
  const unsigned short* Wg = W + (size_t)n0 * Kd;
  f32x4 acc[4][4] = {};
  for (int k0 = 0; k0 < Kd; k0 += 64) {
    stage_tile(Ag + k0, Kd, As, wave, lane);
    stage_tile(Wg + k0, Kd, Bs, wave, lane);
    __syncthreads();
#pragma unroll
    for (int ks = 0; ks < 2; ++ks) {
      bf16x8 a[4], b[4];
#pragma unroll
      for (int fm = 0; fm < 4; ++fm) a[fm] = lds_frag(As, wm * 64 + fm * 16 + lr, ks * 4 + lk);
#pragma unroll
      for (int fn = 0; fn < 4; ++fn) b[fn] = lds_frag(Bs, wn * 64 + fn * 16 + lr, ks * 4 + lk);
#pragma unroll
      for (int fm = 0; fm < 4; ++fm)
#pragma unroll
        for (int fn = 0; fn < 4; ++fn)
          acc[fm][fn] = __builtin_amdgcn_mfma_f32_16x16x32_bf16(a[fm], b[fn], acc[fm][fn], 0, 0, 0);
    }
    __syncthreads();
  }
  int t = n0 >> 10;   // uniform per block (128 | 1024)
  if (t == 2) {
    // V: store transposed -> Vt[bh][d][s]
#pragma unroll
    for (int fm = 0; fm < 4; ++fm) {
      int row = m0 + wm * 64 + fm * 16 + lk * 4;
      int bb = row >> 11, s0 = row & 2047;
#pragma unroll
      for (int fn = 0; fn < 4; ++fn) {
        int col = n0 + wn * 64 + fn * 16 + lr;
        int h = (col >> 6) & 15, d = col & 63;
        uint2 w;
        w.x = pk2(acc[fm][fn][0], acc[fm][fn][1]);
        w.y = pk2(acc[fm][fn][2], acc[fm][fn][3]);
        *reinterpret_cast<uint2*>(Vt + (((size_t)(bb * 16 + h) * 64) + d) * S + s0) = w;
      }
    }
  } else {
    // Q/K: apply RoPE on f32 accumulators (pairs = adjacent lanes), then store.
    unsigned short* dst0 = (t == 0) ? Qh : Kh;
#pragma unroll
    for (int fm = 0; fm < 4; ++fm) {
      int row = m0 + wm * 64 + fm * 16 + lk * 4;
#pragma unroll
      for (int fn = 0; fn < 4; ++fn) {
        int col = n0 + wn * 64 + fn * 16 + lr;
        int h = (col >> 6) & 15, d = col & 63;
        int ri = d >> 1;
        bool odd = d & 1;
#pragma unroll
        for (int r = 0; r < 4; ++r) {
          int rr = row + r;
          int bb = rr >> 11, s = rr & 2047;
          float2 cs = reinterpret_cast<const float2*>(tab)[s * 32 + ri];
          float v = acc[fm][fn][r];
          float other = __shfl_xor(v, 1);
          float res = odd ? (other * cs.y + v * cs.x)     // x1*sin + x2*cos
                          : (v * cs.x - other * cs.y);    // x1*cos - x2*sin
          dst0[(((size_t)(bb * 16 + h) * S) + s) * 64 + d] = f2bf(res);
        }
      }
    }
  }
}

// ---------------- Flash attention (swapped-QK^T, transposed-O) ----------------
// grid (BH=64, 16), 4 waves/block, each wave owns 32 q-rows. K and V^T tiles
// (64x64) staged in LDS, double-buffered via global_load_lds; prefetch(t+1)
// issued before compute(t).
__global__ __launch_bounds__(256) void k_attn(
    const unsigned short* __restrict__ Qh, const unsigned short* __restrict__ Kh,
    const unsigned short* __restrict__ Vt, unsigned short* __restrict__ Obuf) {
  const int S = 2048;
  const float KF = 0.18033688f;          // 0.125 * log2(e)
  const float RAW_THR = 44.3614f;        // 8 log2-units in raw-score domain
  int bh = blockIdx.x;
  int b = bh >> 4, h = bh & 15;
  int wave = threadIdx.x >> 6, lane = threadIdx.x & 63;
  int lr = lane & 15, lk = lane >> 4;
  int qt = (int)gridDim.y - 1 - (int)blockIdx.y;   // heavy tiles dispatch first
  int q0 = qt * 128 + wave * 32;
  const unsigned short* Qp = Qh + (size_t)bh * S * 64;
  const unsigned short* Kp = Kh + (size_t)bh * S * 64;
  const unsigned short* Vp = Vt + (size_t)bh * 64 * S;

  __shared__ __align__(16) unsigned short Ks[2][64 * 64];   // 16 KB
  __shared__ __align__(16) unsigned short Vs[2][64 * 64];   // 16 KB
  __shared__ __align__(16) unsigned short P_all[4][32][64]; // 16 KB
  char* pw = (char*)&P_all[wave][0][0];

  // stage K rows kv0..kv0+63 and V^T rows d=0..63 (cols kv0..) into buf
  auto STAGE = [&](int buf, int kv0) {
    int rl = lane >> 3, c16 = lane & 7;
#pragma unroll
    for (int i = 0; i < 2; ++i) {
      int row = wave * 16 + i * 8 + rl;
      int sc = (c16 ^ (row & 7)) << 3;
      gload_lds16(Kp + (size_t)(kv0 + row) * 64 + sc, &Ks[buf][(wave * 16 + i * 8) * 64]);
      gload_lds16(Vp + (size_t)row * S + kv0 + sc,    &Vs[buf][(wave * 16 + i * 8) * 64]);
    }
  };

  bf16x8 qb[2][2];
#pragma unroll
  for (int mi = 0; mi < 2; ++mi)
#pragma unroll
    for (int ks = 0; ks < 2; ++ks)
      qb[mi][ks] = ld_bf8(Qp + (size_t)(q0 + mi * 16 + lr) * 64 + ks * 32 + lk * 8);

  f32x4 acc_o[4][2] = {};                 // O^T: [nf=d-blk][mi]: row=d, col=q
  float m_run[2] = {-1e30f, -1e30f}, l_run[2] = {0.f, 0.f};
  int my_nt = (q0 + 31) / 64 + 1;
  int NT = 2 * qt + 2;                    // max ntiles over the 4 waves

  STAGE(0, 0);
  __syncthreads();                        // drains vmcnt -> buf0 ready

  for (int t = 0; t < NT; ++t) {
    int cur = t & 1;
    if (t + 1 < NT) STAGE(cur ^ 1, (t + 1) * 64);   // async prefetch next tile
    if (t < my_nt) {
      int kv0 = t * 64;
      // K fragments from LDS (A operand of S^T = K·Q^T)
      bf16x8 ka[4][2];
#pragma unroll
      for (int ni = 0; ni < 4; ++ni)
#pragma unroll
        for (int ks = 0; ks < 2; ++ks)
          ka[ni][ks] = lds_frag(&Ks[cur][0], ni * 16 + lr, ks * 4 + lk);
      f32x4 st[4][2] = {};
      __builtin_amdgcn_s_setprio(1);
#pragma unroll
      for (int ni = 0; ni < 4; ++ni)
#pragma unroll
        for (int mi = 0; mi < 2; ++mi) {
          st[ni][mi] = __builtin_amdgcn_mfma_f32_16x16x32_bf16(ka[ni][0], qb[mi][0], st[ni][mi], 0, 0, 0);
          st[ni][mi] = __builtin_amdgcn_mfma_f32_16x16x32_bf16(ka[ni][1], qb[mi][1], st[ni][mi], 0, 0, 0);
        }
      __builtin_amdgcn_s_setprio(0);
      // V fragments (A operand of O^T = V^T·P^T) — ds_read returns under softmax
      bf16x8 va[4][2];
#pragma unroll
      for (int nf = 0; nf < 4; ++nf)
#pragma unroll
        for (int ks = 0; ks < 2; ++ks)
          va[nf][ks] = lds_frag(&Vs[cur][0], nf * 16 + lr, ks * 4 + lk);

      if (kv0 + 63 > q0) {   // causal mask (wave-uniform branch)
#pragma unroll
        for (int mi = 0; mi < 2; ++mi) {
          int row = q0 + mi * 16 + lr;
#pragma unroll
          for (int ni = 0; ni < 4; ++ni)
#pragma unroll
            for (int r = 0; r < 4; ++r)
              if (kv0 + ni * 16 + lk * 4 + r > row) st[ni][mi][r] = -3e38f;
        }
      }
      // per-lane row max (in-lane tree + 2 shfl)
      float mx[2];
#pragma unroll
      for (int mi = 0; mi < 2; ++mi) {
        float a0 = fmaxf(fmaxf(st[0][mi][0], st[0][mi][1]), fmaxf(st[0][mi][2], st[0][mi][3]));
        float a1 = fmaxf(fmaxf(st[1][mi][0], st[1][mi][1]), fmaxf(st[1][mi][2], st[1][mi][3]));
        float a2 = fmaxf(fmaxf(st[2][mi][0], st[2][mi][1]), fmaxf(st[2][mi][2], st[2][mi][3]));
        float a3 = fmaxf(fmaxf(st[3][mi][0], st[3][mi][1]), fmaxf(st[3][mi][2], st[3][mi][3]));
        float m = fmaxf(fmaxf(a0, a1), fmaxf(a2, a3));
        m = fmaxf(m, __shfl_xor(m, 16));
        m = fmaxf(m, __shfl_xor(m, 32));
        mx[mi] = m;
      }
      // defer-max (T13): rescale only if some row's max grew past threshold
      bool small = (mx[0] <= m_run[0] + RAW_THR) && (mx[1] <= m_run[1] + RAW_THR);
      if (!__all(small)) {
#pragma unroll
        for (int mi = 0; mi < 2; ++mi) {
          float m_new = fmaxf(m_run[mi], mx[mi]);
          float scale = __builtin_amdgcn_exp2f((m_run[mi] - m_new) * KF);
          l_run[mi] *= scale;
          m_run[mi] = m_new;
#pragma unroll
          for (int nf = 0; nf < 4; ++nf)
#pragma unroll
            for (int r = 0; r < 4; ++r) acc_o[nf][mi][r] *= scale;
        }
      }
      // P = exp2(st*KF - m*KF), HW-packed bf16, swizzled 8B LDS writes
#pragma unroll
      for (int mi = 0; mi < 2; ++mi) {
        float negh = -m_run[mi] * KF;
        int prow = mi * 16 + lr;
        char* rowp = pw + prow * 128;
        int swz = (lr & 7) << 4;
        float rs = 0.f;
#pragma unroll
        for (int ni = 0; ni < 4; ++ni) {
          float p0 = __builtin_amdgcn_exp2f(fmaf(st[ni][mi][0], KF, negh));
          float p1 = __builtin_amdgcn_exp2f(fmaf(st[ni][mi][1], KF, negh));
          float p2 = __builtin_amdgcn_exp2f(fmaf(st[ni][mi][2], KF, negh));
          float p3 = __builtin_amdgcn_exp2f(fmaf(st[ni][mi][3], KF, negh));
          rs += (p0 + p1) + (p2 + p3);
          uint2 w; w.x = pk2(p0, p1); w.y = pk2(p2, p3);
          *reinterpret_cast<uint2*>(rowp + ((ni * 32 + lk * 8) ^ swz)) = w;
        }
        rs += __shfl_xor(rs, 16);
        rs += __shfl_xor(rs, 32);
        l_run[mi] += rs;
      }
      // PV: O^T += V^T · P^T  (P as B operand from swizzled LDS)
      bf16x8 pb[2][2];
#pragma unroll
      for (int mi = 0; mi < 2; ++mi) {
        int prow = mi * 16 + lr;
        int swz = (lr & 7) << 4;
#pragma unroll
        for (int ks = 0; ks < 2; ++ks)
          pb[mi][ks] = ld_bf8((const unsigned short*)(pw + prow * 128 + ((ks * 64 + lk * 16) ^ swz)));
      }
      __builtin_amdgcn_s_setprio(1);
#pragma unroll
      for (int nf = 0; nf < 4; ++nf)
#pragma unroll
        for (int mi = 0; mi < 2; ++mi) {
          acc_o[nf][mi] = __builtin_amdgcn_mfma_f32_16x16x32_bf16(va[nf][0], pb[mi][0], acc_o[nf][mi], 0, 0, 0);
          acc_o[nf][mi] = __builtin_amdgcn_mfma_f32_16x16x32_bf16(va[nf][1], pb[mi][1], acc_o[nf][mi], 0, 0, 0);
        }
      __builtin_amdgcn_s_setprio(0);
    }
    __syncthreads();   // drains vmcnt (stage done) + orders LDS reuse
  }

  // epilogue: O[q][d] = O^T[d][q] / l ; packed 8B stores
#pragma unroll
  for (int mi = 0; mi < 2; ++mi) {
    float inv_l = 1.f / l_run[mi];
    int q = q0 + mi * 16 + lr;
    size_t base = ((size_t)b * S + q) * 1024 + h * 64;
#pragma unroll
    for (int nf = 0; nf < 4; ++nf) {
      uint2 w;
      w.x = pk2(acc_o[nf][mi][0] * inv_l, acc_o[nf][mi][1] * inv_l);
      w.y = pk2(acc_o[nf][mi][2] * inv_l, acc_o[nf][mi][3] * inv_l);
      *reinterpret_cast<uint2*>(Obuf + base + nf * 16 + lk * 4) = w;
    }
  }
}

// ---------------- Output GEMM: Obuf[8192x1024] @ Wo[1024x1024]^T -> f32 ----------------
__global__ __launch_bounds__(256) void k_gemm_out(
    const unsigned short* __restrict__ A, const unsigned short* __restrict__ W,
    float* __restrict__ C) {
  const int Kd = 1024;
  __shared__ __align__(16) unsigned short As[128 * 64];
  __shared__ __align__(16) unsigned short Bs[128 * 64];
  int m0 = blockIdx.x * 128, n0 = blockIdx.y * 128;
  int wave = threadIdx.x >> 6, lane = threadIdx.x & 63;
  int wm = wave >> 1, wn = wave & 1;
  int lr = lane & 15, lk = lane >> 4;
  const unsigned short* Ag = A + (size_t)m0 * Kd;
  const unsigned short* Wg = W + (size_t)n0 * Kd;
  f32x4 acc[4][4] = {};
  for (int k0 = 0; k0 < Kd; k0 += 64) {
    stage_tile(Ag + k0, Kd, As, wave, lane);
    stage_tile(Wg + k0, Kd, Bs, wave, lane);
    __syncthreads();
#pragma unroll
    for (int ks = 0; ks < 2; ++ks) {
      bf16x8 a[4], b[4];
#pragma unroll
      for (int fm = 0; fm < 4; ++fm) a[fm] = lds_frag(As, wm * 64 + fm * 16 + lr, ks * 4 + lk);
#pragma unroll
      for (int fn = 0; fn < 4; ++fn) b[fn] = lds_frag(Bs, wn * 64 + fn * 16 + lr, ks * 4 + lk);
#pragma unroll
      for (int fm = 0; fm < 4; ++fm)
#pragma unroll
        for (int fn = 0; fn < 4; ++fn)
          acc[fm][fn] = __builtin_amdgcn_mfma_f32_16x16x32_bf16(a[fm], b[fn], acc[fm][fn], 0, 0, 0);
    }
    __syncthreads();
  }
#pragma unroll
  for (int fm = 0; fm < 4; ++fm)
#pragma unroll
    for (int fn = 0; fn < 4; ++fn)
#pragma unroll
      for (int r = 0; r < 4; ++r)
        C[(size_t)(m0 + wm * 64 + fm * 16 + lk * 4 + r) * 1024 + n0 + wn * 64 + fn * 16 + lr] =
            acc[fm][fn][r];
}

extern "C" void kernel_launch(void* const* d_in, const int* in_sizes, int n_in,
                              void* d_out, int out_size, void* d_ws, size_t ws_size,
                              hipStream_t stream) {
  const float* x  = (const float*)d_in[0];
  const float* Wq = (const float*)d_in[1];
  const float* Wk = (const float*)d_in[2];
  const float* Wv = (const float*)d_in[3];
  const float* Wo = (const float*)d_in[4];
  const int* pos  = (const int*)d_in[5];
  float* out = (float*)d_out;
  char* ws = (char*)d_ws;

  // Workspace layout (bytes):
  unsigned short* xb  = (unsigned short*)(ws);              // 16 MB  x bf16 [8192][1024]
  unsigned short* Wb  = (unsigned short*)(ws + 16777216);   // 6 MB   Wq|Wk|Wv bf16 [3072][1024]
  unsigned short* Wob = (unsigned short*)(ws + 23068672);   // 2 MB   Wo bf16
  unsigned short* Qh  = (unsigned short*)(ws + 25165824);   // 16 MB  [B][H][S][64]
  unsigned short* Kh  = (unsigned short*)(ws + 41943040);   // 16 MB
  unsigned short* Ob  = (unsigned short*)(ws + 58720256);   // 16 MB  attn out bf16
  unsigned short* Vt  = (unsigned short*)(ws + 75497472);   // 16 MB  [B][H][64][S]
  float* tab          = (float*)(ws + 92274688);            // 512 KB cos/sin
  (void)in_sizes; (void)n_in; (void)out_size; (void)ws_size;

  k_f32_to_bf16<<<8192, 256, 0, stream>>>(x, xb, 2097152);
  k_conv_w<<<4096, 256, 0, stream>>>(Wq, Wk, Wv, Wo, Wb, Wob);
  k_rope_table<<<256, 256, 0, stream>>>(pos, tab);

  dim3 g1(64, 24);
  k_gemm_qkv<<<g1, 256, 0, stream>>>(xb, Wb, Qh, Kh, Vt, tab);
  dim3 ga(64, 16);
  k_attn<<<ga, 256, 0, stream>>>(Qh, Kh, Vt, Ob);
  dim3 g2(64, 8);
  k_gemm_out<<<g2, 256, 0, stream>>>(Ob, Wob, out);
}